// Round 6
// baseline (316.769 us; speedup 1.0000x reference)
//
#include <hip/hip_runtime.h>
#include <math.h>

#define NN 50000
#define NE 800000
#define CH 64
#define SCAN_BLK 1024
#define NB1 ((NN + SCAN_BLK - 1) / SCAN_BLK)  // 49

typedef float v4f __attribute__((ext_vector_type(4)));

// ---------------- counting-sort pipeline (atomic-free aggregation) ----------

// 1) histogram of dst
__global__ __launch_bounds__(256) void hist_k(const int* __restrict__ ei,
                                              int* __restrict__ count) {
    int i = blockIdx.x * 256 + threadIdx.x;
    const int stride = gridDim.x * 256;
    for (int e = i; e < NE; e += stride)
        atomicAdd(&count[ei[NE + e]], 1);
}

// 2a) per-block (1024-elem) local exclusive scan + block total
__global__ __launch_bounds__(256) void scan1_k(const int* __restrict__ count,
                                               int* __restrict__ start,
                                               int* __restrict__ blockSum) {
    __shared__ int lds[256];
    const int t = threadIdx.x;
    const int base = blockIdx.x * SCAN_BLK + t * 4;
    int c0 = 0, c1 = 0, c2 = 0, c3 = 0;
    if (base + 3 < NN) {
        int4 v = *(const int4*)(count + base);
        c0 = v.x; c1 = v.y; c2 = v.z; c3 = v.w;
    } else {
        if (base + 0 < NN) c0 = count[base + 0];
        if (base + 1 < NN) c1 = count[base + 1];
        if (base + 2 < NN) c2 = count[base + 2];
    }
    const int tsum = c0 + c1 + c2 + c3;
    lds[t] = tsum;
    __syncthreads();
    for (int off = 1; off < 256; off <<= 1) {
        int add = (t >= off) ? lds[t - off] : 0;
        __syncthreads();
        lds[t] += add;
        __syncthreads();
    }
    if (t == 255) blockSum[blockIdx.x] = lds[255];
    int r = lds[t] - tsum;  // thread-exclusive base within block
    if (base + 0 < NN) start[base + 0] = r; r += c0;
    if (base + 1 < NN) start[base + 1] = r; r += c1;
    if (base + 2 < NN) start[base + 2] = r; r += c2;
    if (base + 3 < NN) start[base + 3] = r;
}

// 2b) single-wave scan of the 49 block sums
__global__ __launch_bounds__(64) void scan2_k(const int* __restrict__ blockSum,
                                              int* __restrict__ blockOff,
                                              int* __restrict__ start) {
    const int t = threadIdx.x;
    const int orig = (t < NB1) ? blockSum[t] : 0;
    int v = orig;
    for (int off = 1; off < 64; off <<= 1) {
        int n = __shfl_up(v, off, 64);
        if (t >= off) v += n;
    }
    if (t < NB1) blockOff[t] = v - orig;   // exclusive
    if (t == NB1 - 1) start[NN] = v;       // total == NE
}

// 2c) add block offsets; materialize cursor
__global__ __launch_bounds__(256) void scan3_k(int* __restrict__ start,
                                               int* __restrict__ cursor,
                                               const int* __restrict__ blockOff) {
    const int t = threadIdx.x;
    const int base = blockIdx.x * SCAN_BLK + t * 4;
    const int off = blockOff[blockIdx.x];
    if (base + 3 < NN) {
        int4 v = *(const int4*)(start + base);
        v.x += off; v.y += off; v.z += off; v.w += off;
        *(int4*)(start + base) = v;
        *(int4*)(cursor + base) = v;
    } else {
        for (int k = 0; k < 4; ++k)
            if (base + k < NN) {
                int v = start[base + k] + off;
                start[base + k] = v;
                cursor[base + k] = v;
            }
    }
}

// 3) place packed (src, norm) into dst-sorted order — one 8B store per edge
__global__ __launch_bounds__(256) void place_k(const int* __restrict__ ei,
                                               const float* __restrict__ ea,
                                               int* __restrict__ cursor,
                                               int2* __restrict__ pp) {
    int i = blockIdx.x * 256 + threadIdx.x;
    const int stride = gridDim.x * 256;
    for (int e = i; e < NE; e += stride) {
        const int src = ei[e];
        const int dst = ei[NE + e];
        const float a0 = ea[3 * e + 0];
        const float a1 = ea[3 * e + 1];
        const float a2 = ea[3 * e + 2];
        const float nrm = sqrtf(a0 * a0 + a1 * a1 + a2 * a2);
        const int pos = atomicAdd(&cursor[dst], 1);
        int2 pr; pr.x = src; pr.y = __float_as_int(nrm);
        pp[pos] = pr;
    }
}

// 4) per-node register accumulation: s[n,c] = sum_{e in seg(n)} nrm_e * x[src_e, c]
//    One wave per node, lane = channel; 8-deep unrolled gathers (2KB in
//    flight/wave) to hide L2/L3 latency. Zero f32 atomics.
__global__ __launch_bounds__(256) void agg_k(const float* __restrict__ x,
                                             const int* __restrict__ start,
                                             const int2* __restrict__ pp,
                                             float* __restrict__ s) {
    const int c = threadIdx.x & 63;
    int w = (int)((blockIdx.x * 256u + threadIdx.x) >> 6);
    const int nw = (int)((gridDim.x * 256u) >> 6);
    for (int n = w; n < NN; n += nw) {
        const int b = start[n];
        const int e = start[n + 1];
        float acc0 = 0.f, acc1 = 0.f;
        int j = b;
        for (; j + 8 <= e; j += 8) {
            const int2 p0 = pp[j],     p1 = pp[j + 1], p2 = pp[j + 2], p3 = pp[j + 3];
            const int2 p4 = pp[j + 4], p5 = pp[j + 5], p6 = pp[j + 6], p7 = pp[j + 7];
            const float x0 = x[(size_t)p0.x * CH + c];
            const float x1 = x[(size_t)p1.x * CH + c];
            const float x2 = x[(size_t)p2.x * CH + c];
            const float x3 = x[(size_t)p3.x * CH + c];
            const float x4 = x[(size_t)p4.x * CH + c];
            const float x5 = x[(size_t)p5.x * CH + c];
            const float x6 = x[(size_t)p6.x * CH + c];
            const float x7 = x[(size_t)p7.x * CH + c];
            acc0 = fmaf(__int_as_float(p0.y), x0, acc0);
            acc1 = fmaf(__int_as_float(p1.y), x1, acc1);
            acc0 = fmaf(__int_as_float(p2.y), x2, acc0);
            acc1 = fmaf(__int_as_float(p3.y), x3, acc1);
            acc0 = fmaf(__int_as_float(p4.y), x4, acc0);
            acc1 = fmaf(__int_as_float(p5.y), x5, acc1);
            acc0 = fmaf(__int_as_float(p6.y), x6, acc0);
            acc1 = fmaf(__int_as_float(p7.y), x7, acc1);
        }
        for (; j < e; ++j) {
            const int2 p = pp[j];
            acc0 = fmaf(__int_as_float(p.y), x[(size_t)p.x * CH + c], acc0);
        }
        s[(size_t)n * CH + c] = acc0 + acc1;
    }
}

// ---------------- fallback scatter (round-2 proven, atomic-rate bound) ------
__global__ __launch_bounds__(256) void scatter_r2(const float* __restrict__ x,
                                                  const int* __restrict__ ei,
                                                  const float* __restrict__ ea,
                                                  float* s) {
    const int lane = threadIdx.x & 63;
    int w = (int)((blockIdx.x * 256u + threadIdx.x) >> 6);
    const int nw = (int)((gridDim.x * 256u) >> 6);
    for (int e = w; e < NE; e += nw) {
        const int src = ei[e];
        const int dst = ei[NE + e];
        const float a0 = ea[3 * e + 0];
        const float a1 = ea[3 * e + 1];
        const float a2 = ea[3 * e + 2];
        const float nrm = sqrtf(a0 * a0 + a1 * a1 + a2 * a2);
        atomicAdd(&s[(size_t)dst * CH + lane], nrm * x[(size_t)src * CH + lane]);
    }
}

// ---------------- epilogue: out[n,o] = x[n,:]·psi[o,:] + s[n,:]·phi[o,:] ----
// Weights-in-registers. __launch_bounds__(256, 1) lifts the VGPR cap so the
// 32 weight v4fs actually STAY in registers (round-5 profile: default bounds
// gave VGPR=84 -> compiler rematerialized weight loads per row -> 61 µs
// latency-bound). 4 independent FMA chains; grid-stride over 16384 waves.
// s may alias out (row fully read before its store; rows wave-exclusive).
__global__ __launch_bounds__(256, 1) void out_k(const float* __restrict__ x,
                                                const float* s,
                                                const float* __restrict__ phi,
                                                const float* __restrict__ psi,
                                                float* out) {
    const int o = threadIdx.x & 63;
    const int wave = (int)((blockIdx.x * 256u + threadIdx.x) >> 6);
    const int nwave = (int)((gridDim.x * 256u) >> 6);

    v4f wpsi[16], wphi[16];
#pragma unroll
    for (int i4 = 0; i4 < 16; ++i4) {
        wpsi[i4] = *(const v4f*)(psi + (size_t)o * CH + 4 * i4);
        wphi[i4] = *(const v4f*)(phi + (size_t)o * CH + 4 * i4);
    }

    for (int n = wave; n < NN; n += nwave) {
        const v4f* xp = (const v4f*)(x + (size_t)n * CH);
        const v4f* sp = (const v4f*)(s + (size_t)n * CH);
        float a0 = 0.f, a1 = 0.f, a2 = 0.f, a3 = 0.f;
#pragma unroll
        for (int i4 = 0; i4 < 16; i4 += 2) {
            v4f xv = xp[i4], xw = xp[i4 + 1];
            v4f sv = sp[i4], sw = sp[i4 + 1];
            a0 = fmaf(xv.x, wpsi[i4].x, a0);
            a0 = fmaf(xv.y, wpsi[i4].y, a0);
            a0 = fmaf(xv.z, wpsi[i4].z, a0);
            a0 = fmaf(xv.w, wpsi[i4].w, a0);
            a1 = fmaf(xw.x, wpsi[i4 + 1].x, a1);
            a1 = fmaf(xw.y, wpsi[i4 + 1].y, a1);
            a1 = fmaf(xw.z, wpsi[i4 + 1].z, a1);
            a1 = fmaf(xw.w, wpsi[i4 + 1].w, a1);
            a2 = fmaf(sv.x, wphi[i4].x, a2);
            a2 = fmaf(sv.y, wphi[i4].y, a2);
            a2 = fmaf(sv.z, wphi[i4].z, a2);
            a2 = fmaf(sv.w, wphi[i4].w, a2);
            a3 = fmaf(sw.x, wphi[i4 + 1].x, a3);
            a3 = fmaf(sw.y, wphi[i4 + 1].y, a3);
            a3 = fmaf(sw.z, wphi[i4 + 1].z, a3);
            a3 = fmaf(sw.w, wphi[i4 + 1].w, a3);
        }
        out[(size_t)n * CH + o] = (a0 + a1) + (a2 + a3);
    }
}

extern "C" void kernel_launch(void* const* d_in, const int* in_sizes, int n_in,
                              void* d_out, int out_size, void* d_ws, size_t ws_size,
                              hipStream_t stream) {
    const float* x   = (const float*)d_in[0];
    const int*   ei  = (const int*)d_in[1];
    const float* ea  = (const float*)d_in[2];
    const float* phi = (const float*)d_in[3];
    const float* psi = (const float*)d_in[4];
    float* out = (float*)d_out;

    // ws layout (8B-aligned first): pair[NE] | count[NN] | start[NN+1] |
    //                               cursor[NN] | blockSum[64] | blockOff[64]
    const size_t need = (size_t)NE * 8 + ((size_t)NN + (NN + 1) + NN + 128) * 4;

    if (ws_size >= need) {
        int2* pp    = (int2*)d_ws;
        int* count  = (int*)(pp + NE);
        int* start  = count + NN;
        int* cursor = start + (NN + 1);
        int* blockSum = cursor + NN;
        int* blockOff = blockSum + 64;

        (void)hipMemsetAsync(count, 0, (size_t)NN * sizeof(int), stream);
        hist_k<<<1024, 256, 0, stream>>>(ei, count);
        scan1_k<<<NB1, 256, 0, stream>>>(count, start, blockSum);
        scan2_k<<<1, 64, 0, stream>>>(blockSum, blockOff, start);
        scan3_k<<<NB1, 256, 0, stream>>>(start, cursor, blockOff);
        place_k<<<1024, 256, 0, stream>>>(ei, ea, cursor, pp);
        agg_k<<<2048, 256, 0, stream>>>(x, start, pp, out);  // s lives in out
        out_k<<<4096, 256, 0, stream>>>(x, out, phi, psi, out);
    } else {
        // fallback: proven round-2 path (atomic-rate bound)
        (void)hipMemsetAsync(out, 0, (size_t)NN * CH * sizeof(float), stream);
        scatter_r2<<<4096, 256, 0, stream>>>(x, ei, ea, out);
        out_k<<<4096, 256, 0, stream>>>(x, out, phi, psi, out);
    }
}

// Round 7
// 274.482 us; speedup vs baseline: 1.1541x; 1.1541x over previous
//
#include <hip/hip_runtime.h>
#include <math.h>

#define NN 50000
#define NE 800000
#define CH 64
#define SCAN_BLK 1024
#define NB1 ((NN + SCAN_BLK - 1) / SCAN_BLK)  // 49

typedef float v4f __attribute__((ext_vector_type(4)));

// ---------------- counting-sort pipeline (atomic-free aggregation) ----------

// 1) histogram of dst
__global__ __launch_bounds__(256) void hist_k(const int* __restrict__ ei,
                                              int* __restrict__ count) {
    int i = blockIdx.x * 256 + threadIdx.x;
    const int stride = gridDim.x * 256;
    for (int e = i; e < NE; e += stride)
        atomicAdd(&count[ei[NE + e]], 1);
}

// 2a) per-block (1024-elem) local exclusive scan + block total
__global__ __launch_bounds__(256) void scan1_k(const int* __restrict__ count,
                                               int* __restrict__ start,
                                               int* __restrict__ blockSum) {
    __shared__ int lds[256];
    const int t = threadIdx.x;
    const int base = blockIdx.x * SCAN_BLK + t * 4;
    int c0 = 0, c1 = 0, c2 = 0, c3 = 0;
    if (base + 3 < NN) {
        int4 v = *(const int4*)(count + base);
        c0 = v.x; c1 = v.y; c2 = v.z; c3 = v.w;
    } else {
        if (base + 0 < NN) c0 = count[base + 0];
        if (base + 1 < NN) c1 = count[base + 1];
        if (base + 2 < NN) c2 = count[base + 2];
    }
    const int tsum = c0 + c1 + c2 + c3;
    lds[t] = tsum;
    __syncthreads();
    for (int off = 1; off < 256; off <<= 1) {
        int add = (t >= off) ? lds[t - off] : 0;
        __syncthreads();
        lds[t] += add;
        __syncthreads();
    }
    if (t == 255) blockSum[blockIdx.x] = lds[255];
    int r = lds[t] - tsum;  // thread-exclusive base within block
    if (base + 0 < NN) start[base + 0] = r; r += c0;
    if (base + 1 < NN) start[base + 1] = r; r += c1;
    if (base + 2 < NN) start[base + 2] = r; r += c2;
    if (base + 3 < NN) start[base + 3] = r;
}

// 2b) single-wave scan of the 49 block sums
__global__ __launch_bounds__(64) void scan2_k(const int* __restrict__ blockSum,
                                              int* __restrict__ blockOff,
                                              int* __restrict__ start) {
    const int t = threadIdx.x;
    const int orig = (t < NB1) ? blockSum[t] : 0;
    int v = orig;
    for (int off = 1; off < 64; off <<= 1) {
        int n = __shfl_up(v, off, 64);
        if (t >= off) v += n;
    }
    if (t < NB1) blockOff[t] = v - orig;   // exclusive
    if (t == NB1 - 1) start[NN] = v;       // total == NE
}

// 2c) add block offsets; materialize cursor
__global__ __launch_bounds__(256) void scan3_k(int* __restrict__ start,
                                               int* __restrict__ cursor,
                                               const int* __restrict__ blockOff) {
    const int t = threadIdx.x;
    const int base = blockIdx.x * SCAN_BLK + t * 4;
    const int off = blockOff[blockIdx.x];
    if (base + 3 < NN) {
        int4 v = *(const int4*)(start + base);
        v.x += off; v.y += off; v.z += off; v.w += off;
        *(int4*)(start + base) = v;
        *(int4*)(cursor + base) = v;
    } else {
        for (int k = 0; k < 4; ++k)
            if (base + k < NN) {
                int v = start[base + k] + off;
                start[base + k] = v;
                cursor[base + k] = v;
            }
    }
}

// 3) place packed (src, norm) into dst-sorted order — one 8B store per edge
__global__ __launch_bounds__(256) void place_k(const int* __restrict__ ei,
                                               const float* __restrict__ ea,
                                               int* __restrict__ cursor,
                                               int2* __restrict__ pp) {
    int i = blockIdx.x * 256 + threadIdx.x;
    const int stride = gridDim.x * 256;
    for (int e = i; e < NE; e += stride) {
        const int src = ei[e];
        const int dst = ei[NE + e];
        const float a0 = ea[3 * e + 0];
        const float a1 = ea[3 * e + 1];
        const float a2 = ea[3 * e + 2];
        const float nrm = sqrtf(a0 * a0 + a1 * a1 + a2 * a2);
        const int pos = atomicAdd(&cursor[dst], 1);
        int2 pr; pr.x = src; pr.y = __float_as_int(nrm);
        pp[pos] = pr;
    }
}

// 4) per-node register accumulation: s[n,c] = sum_{e in seg(n)} nrm_e * x[src_e, c]
//    One wave per node, lane = channel; 8-deep unrolled gathers. Zero f32 atomics.
__global__ __launch_bounds__(256) void agg_k(const float* __restrict__ x,
                                             const int* __restrict__ start,
                                             const int2* __restrict__ pp,
                                             float* __restrict__ s) {
    const int c = threadIdx.x & 63;
    int w = (int)((blockIdx.x * 256u + threadIdx.x) >> 6);
    const int nw = (int)((gridDim.x * 256u) >> 6);
    for (int n = w; n < NN; n += nw) {
        const int b = start[n];
        const int e = start[n + 1];
        float acc0 = 0.f, acc1 = 0.f;
        int j = b;
        for (; j + 8 <= e; j += 8) {
            const int2 p0 = pp[j],     p1 = pp[j + 1], p2 = pp[j + 2], p3 = pp[j + 3];
            const int2 p4 = pp[j + 4], p5 = pp[j + 5], p6 = pp[j + 6], p7 = pp[j + 7];
            const float x0 = x[(size_t)p0.x * CH + c];
            const float x1 = x[(size_t)p1.x * CH + c];
            const float x2 = x[(size_t)p2.x * CH + c];
            const float x3 = x[(size_t)p3.x * CH + c];
            const float x4 = x[(size_t)p4.x * CH + c];
            const float x5 = x[(size_t)p5.x * CH + c];
            const float x6 = x[(size_t)p6.x * CH + c];
            const float x7 = x[(size_t)p7.x * CH + c];
            acc0 = fmaf(__int_as_float(p0.y), x0, acc0);
            acc1 = fmaf(__int_as_float(p1.y), x1, acc1);
            acc0 = fmaf(__int_as_float(p2.y), x2, acc0);
            acc1 = fmaf(__int_as_float(p3.y), x3, acc1);
            acc0 = fmaf(__int_as_float(p4.y), x4, acc0);
            acc1 = fmaf(__int_as_float(p5.y), x5, acc1);
            acc0 = fmaf(__int_as_float(p6.y), x6, acc0);
            acc1 = fmaf(__int_as_float(p7.y), x7, acc1);
        }
        for (; j < e; ++j) {
            const int2 p = pp[j];
            acc0 = fmaf(__int_as_float(p.y), x[(size_t)p.x * CH + c], acc0);
        }
        s[(size_t)n * CH + c] = acc0 + acc1;
    }
}

// ---------------- fallback scatter (round-2 proven, atomic-rate bound) ------
__global__ __launch_bounds__(256) void scatter_r2(const float* __restrict__ x,
                                                  const int* __restrict__ ei,
                                                  const float* __restrict__ ea,
                                                  float* s) {
    const int lane = threadIdx.x & 63;
    int w = (int)((blockIdx.x * 256u + threadIdx.x) >> 6);
    const int nw = (int)((gridDim.x * 256u) >> 6);
    for (int e = w; e < NE; e += nw) {
        const int src = ei[e];
        const int dst = ei[NE + e];
        const float a0 = ea[3 * e + 0];
        const float a1 = ea[3 * e + 1];
        const float a2 = ea[3 * e + 2];
        const float nrm = sqrtf(a0 * a0 + a1 * a1 + a2 * a2);
        atomicAdd(&s[(size_t)dst * CH + lane], nrm * x[(size_t)src * CH + lane]);
    }
}

// ---------------- epilogue: out[n,o] = x[n,:]·psi[o,:] + s[n,:]·phi[o,:] ----
// Weights-in-registers, FORCED: each weight v4f is pinned with an empty
// asm volatile("" : "+v") after load — a value that passed through asm cannot
// be rematerialized, so the allocator must keep all 128 weight floats live.
// (r5/r6 evidence: without the pin, VGPR_Count=84/104 < 128 -> compiler
// re-fetched weights per row -> 61/115 µs latency-bound.)
// __launch_bounds__(256,2) caps at 256 VGPR (need ~160). Grid 1024 blocks:
// 4096 waves, ~12 rows each. s may alias out (row fully read before store;
// rows wave-exclusive -> race-free).
__global__ __launch_bounds__(256, 2) void out_k(const float* __restrict__ x,
                                                const float* s,
                                                const float* __restrict__ phi,
                                                const float* __restrict__ psi,
                                                float* out) {
    const int o = threadIdx.x & 63;
    const int wave = (int)((blockIdx.x * 256u + threadIdx.x) >> 6);
    const int nwave = (int)((gridDim.x * 256u) >> 6);

    v4f wpsi[16], wphi[16];
#pragma unroll
    for (int i4 = 0; i4 < 16; ++i4) {
        wpsi[i4] = *(const v4f*)(psi + (size_t)o * CH + 4 * i4);
        wphi[i4] = *(const v4f*)(phi + (size_t)o * CH + 4 * i4);
        asm volatile("" : "+v"(wpsi[i4]), "+v"(wphi[i4]));
    }

    for (int n = wave; n < NN; n += nwave) {
        const v4f* xp = (const v4f*)(x + (size_t)n * CH);
        const v4f* sp = (const v4f*)(s + (size_t)n * CH);
        float a0 = 0.f, a1 = 0.f, a2 = 0.f, a3 = 0.f;
#pragma unroll
        for (int i4 = 0; i4 < 16; i4 += 2) {
            v4f xv = xp[i4], xw = xp[i4 + 1];
            v4f sv = sp[i4], sw = sp[i4 + 1];
            a0 = fmaf(xv.x, wpsi[i4].x, a0);
            a0 = fmaf(xv.y, wpsi[i4].y, a0);
            a0 = fmaf(xv.z, wpsi[i4].z, a0);
            a0 = fmaf(xv.w, wpsi[i4].w, a0);
            a1 = fmaf(xw.x, wpsi[i4 + 1].x, a1);
            a1 = fmaf(xw.y, wpsi[i4 + 1].y, a1);
            a1 = fmaf(xw.z, wpsi[i4 + 1].z, a1);
            a1 = fmaf(xw.w, wpsi[i4 + 1].w, a1);
            a2 = fmaf(sv.x, wphi[i4].x, a2);
            a2 = fmaf(sv.y, wphi[i4].y, a2);
            a2 = fmaf(sv.z, wphi[i4].z, a2);
            a2 = fmaf(sv.w, wphi[i4].w, a2);
            a3 = fmaf(sw.x, wphi[i4 + 1].x, a3);
            a3 = fmaf(sw.y, wphi[i4 + 1].y, a3);
            a3 = fmaf(sw.z, wphi[i4 + 1].z, a3);
            a3 = fmaf(sw.w, wphi[i4 + 1].w, a3);
        }
        out[(size_t)n * CH + o] = (a0 + a1) + (a2 + a3);
    }
}

extern "C" void kernel_launch(void* const* d_in, const int* in_sizes, int n_in,
                              void* d_out, int out_size, void* d_ws, size_t ws_size,
                              hipStream_t stream) {
    const float* x   = (const float*)d_in[0];
    const int*   ei  = (const int*)d_in[1];
    const float* ea  = (const float*)d_in[2];
    const float* phi = (const float*)d_in[3];
    const float* psi = (const float*)d_in[4];
    float* out = (float*)d_out;

    // ws layout (8B-aligned first): pair[NE] | count[NN] | start[NN+1] |
    //                               cursor[NN] | blockSum[64] | blockOff[64]
    const size_t need = (size_t)NE * 8 + ((size_t)NN + (NN + 1) + NN + 128) * 4;

    if (ws_size >= need) {
        int2* pp    = (int2*)d_ws;
        int* count  = (int*)(pp + NE);
        int* start  = count + NN;
        int* cursor = start + (NN + 1);
        int* blockSum = cursor + NN;
        int* blockOff = blockSum + 64;

        (void)hipMemsetAsync(count, 0, (size_t)NN * sizeof(int), stream);
        hist_k<<<1024, 256, 0, stream>>>(ei, count);
        scan1_k<<<NB1, 256, 0, stream>>>(count, start, blockSum);
        scan2_k<<<1, 64, 0, stream>>>(blockSum, blockOff, start);
        scan3_k<<<NB1, 256, 0, stream>>>(start, cursor, blockOff);
        place_k<<<1024, 256, 0, stream>>>(ei, ea, cursor, pp);
        agg_k<<<2048, 256, 0, stream>>>(x, start, pp, out);  // s lives in out
        out_k<<<1024, 256, 0, stream>>>(x, out, phi, psi, out);
    } else {
        // fallback: proven round-2 path (atomic-rate bound)
        (void)hipMemsetAsync(out, 0, (size_t)NN * CH * sizeof(float), stream);
        scatter_r2<<<4096, 256, 0, stream>>>(x, ei, ea, out);
        out_k<<<1024, 256, 0, stream>>>(x, out, phi, psi, out);
    }
}